// Round 3
// baseline (3185.891 us; speedup 1.0000x reference)
//
#include <hip/hip_runtime.h>

// MetaOptNet head: 15-iteration IPM QP (block-diagonal: 10x 150x150) + logits.
// Round 3: paired inversions (2 ways / 768-thread block), fused Schur kernel.
// Deterministic (only LDS u32 atomicMin used).

#define NW    10
#define NSH   15
#define NSUP  150
#define NQ    8192
#define DIM   1024
#define NVAR  1500
#define NP    152          // padded matrix dim (identity padding)
#define NTT   19           // 8x8 tiles per dim
#define NACT  (NTT*NTT)    // 361 active threads per inversion
#define HALF  384
#define TPB   768
#define SIGMA 0.1f
#define PSTR  68           // LDS panel row stride (64 + 4 pad)

// ws offsets (floats)
#define OFF_K     0        // K stored [150][NP]
#define OFF_Z     22800
#define OFF_S     24300
#define OFF_LAM   25800
#define OFF_NU    27300
#define OFF_R1    27452
#define OFF_DZ    28952
#define OFF_DLAM  30452
#define OFF_RP    31952
#define OFF_MU    32102
#define OFF_LP    32104
#define OFF_WT    34152
#define OFF_G     44392    // G[i*10+a] = (X_a r1_a)_i
#define OFF_X     46000
#define XSZ       (NP*NP)  // 23104

// ---------------- blocked Gauss-Jordan inversion (19 rank-8 steps) -------------------
// th: per-matrix thread id (0..383+ ; gates select <=361). Barriers are block-wide:
// ALL threads of the block must call this in lockstep (both halves when paired).
__device__ __forceinline__ void bgj_invert(float (&H)[8][8], const int th, const int tr, const int tc,
                                           float (*rowbuf)[PSTR], float (*colbuf)[PSTR],
                                           float (*wbuf)[PSTR], float* pivinv) {
  const bool act = (th < NACT);
  for (int kb = 0; kb < NTT; ++kb) {
    if (act && tr == kb) {
      float4* dst = (float4*)(&rowbuf[tc][0]);
#pragma unroll
      for (int r = 0; r < 8; ++r) {
        dst[2*r]   = make_float4(H[r][0],H[r][1],H[r][2],H[r][3]);
        dst[2*r+1] = make_float4(H[r][4],H[r][5],H[r][6],H[r][7]);
      }
    }
    if (act && tc == kb) {
      float4* dst = (float4*)(&colbuf[tr][0]);
#pragma unroll
      for (int r = 0; r < 8; ++r) {
        dst[2*r]   = make_float4(H[r][0],H[r][1],H[r][2],H[r][3]);
        dst[2*r+1] = make_float4(H[r][4],H[r][5],H[r][6],H[r][7]);
      }
    }
    __syncthreads();
    if (th < 64) {                      // one wave: shuffle-based 8x8 GJ inverse
      const int r = th >> 3, c = th & 7;
      float p = rowbuf[kb][th];
#pragma unroll
      for (int pp = 0; pp < 8; ++pp) {
        const float pv   = __shfl(p, pp*9, 64);
        const float d    = 1.0f / pv;
        const float rowv = __shfl(p, pp*8 + c, 64);
        const float colv = __shfl(p, r*8 + pp, 64);
        const float nr   = rowv * d;
        float v = fmaf(-colv, nr, p);
        if (r == pp) v = nr;
        if (c == pp) v = -colv * d;
        if (r == pp && c == pp) v = d;
        p = v;
      }
      pivinv[th] = p;
    }
    __syncthreads();
    if (th < 304) {                     // W = Pinv * R, 4 cols per thread
      const int r8 = th & 7, wj2 = th >> 3;       // wj2 0..37
      const int jb = wj2 >> 1, jh = (wj2 & 1) * 4;
      float w0, w1, w2, w3;
      if (jb == kb) {
        w0 = pivinv[r8*8+jh+0]; w1 = pivinv[r8*8+jh+1];
        w2 = pivinv[r8*8+jh+2]; w3 = pivinv[r8*8+jh+3];
      } else {
        w0 = w1 = w2 = w3 = 0.0f;
#pragma unroll
        for (int q = 0; q < 8; ++q) {
          const float pq = pivinv[r8*8+q];
          const float4 x = *(const float4*)(&rowbuf[jb][q*8+jh]);
          w0 = fmaf(pq, x.x, w0); w1 = fmaf(pq, x.y, w1);
          w2 = fmaf(pq, x.z, w2); w3 = fmaf(pq, x.w, w3);
        }
      }
      *(float4*)(&wbuf[jb][r8*8+jh]) = make_float4(w0,w1,w2,w3);
    }
    __syncthreads();
    if (act) {
      if (tr == kb) {
        const float4* wsrc = (const float4*)(&wbuf[tc][0]);
#pragma unroll
        for (int r = 0; r < 8; ++r) {
          const float4 x = wsrc[2*r], y = wsrc[2*r+1];
          H[r][0]=x.x; H[r][1]=x.y; H[r][2]=x.z; H[r][3]=x.w;
          H[r][4]=y.x; H[r][5]=y.y; H[r][6]=y.z; H[r][7]=y.w;
        }
      } else {
        float C[8][8];
        const float4* cs = (const float4*)(&colbuf[tr][0]);
#pragma unroll
        for (int r = 0; r < 8; ++r) {
          const float4 x = cs[2*r], y = cs[2*r+1];
          C[r][0]=x.x; C[r][1]=x.y; C[r][2]=x.z; C[r][3]=x.w;
          C[r][4]=y.x; C[r][5]=y.y; C[r][6]=y.z; C[r][7]=y.w;
        }
        if (tc == kb) {
#pragma unroll
          for (int r = 0; r < 8; ++r)
#pragma unroll
            for (int c = 0; c < 8; ++c) H[r][c] = 0.0f;
        }
        const float4* wsrc = (const float4*)(&wbuf[tc][0]);
#pragma unroll
        for (int q = 0; q < 8; ++q) {
          const float4 x = wsrc[2*q], y = wsrc[2*q+1];
          const float w0=x.x,w1=x.y,w2=x.z,w3=x.w,w4=y.x,w5=y.y,w6=y.z,w7=y.w;
#pragma unroll
          for (int r = 0; r < 8; ++r) {
            const float cq = C[r][q];
            H[r][0]=fmaf(-cq,w0,H[r][0]); H[r][1]=fmaf(-cq,w1,H[r][1]);
            H[r][2]=fmaf(-cq,w2,H[r][2]); H[r][3]=fmaf(-cq,w3,H[r][3]);
            H[r][4]=fmaf(-cq,w4,H[r][4]); H[r][5]=fmaf(-cq,w5,H[r][5]);
            H[r][6]=fmaf(-cq,w6,H[r][6]); H[r][7]=fmaf(-cq,w7,H[r][7]);
          }
        }
      }
    }
    __syncthreads();
  }
}

// ---------------- K = support @ support^T (150x150, stride NP) -----------------------
__global__ __launch_bounds__(256) void k_gram(const float* __restrict__ feat, float* __restrict__ ws) {
  const int bi = blockIdx.x / 10, bj = blockIdx.x % 10;
  const int t = threadIdx.x;
  const int r = t / 15, c = t % 15;
  const bool act = (t < 225);
  __shared__ float As[15][65], Bs[15][65];
  float acc = 0.0f;
  for (int ch = 0; ch < 16; ++ch) {
    for (int idx = t; idx < 960; idx += 256) {
      const int rr = idx >> 6, dd = idx & 63;
      As[rr][dd] = feat[(bi*15+rr)*DIM + ch*64 + dd];
      Bs[rr][dd] = feat[(bj*15+rr)*DIM + ch*64 + dd];
    }
    __syncthreads();
    if (act) {
      for (int dd = 0; dd < 64; ++dd) acc += As[r][dd] * Bs[c][dd];
    }
    __syncthreads();
  }
  if (act) ws[OFF_K + (bi*15+r)*NP + (bj*15+c)] = acc;
}

// ---------------- init ----------------------------------------------------------------
__global__ __launch_bounds__(1024) void kinit(const int* __restrict__ labSup, float* __restrict__ ws) {
  const int t = threadIdx.x;
  for (int idx = t; idx < NVAR; idx += 1024) {
    const int i = idx / NW, aa = idx % NW;
    const float y = (labSup[i/NSH] == aa) ? 1.0f : 0.0f;
    ws[OFF_Z+idx]   = 0.1f*y - 1.0f;
    ws[OFF_S+idx]   = 1.0f;
    ws[OFF_LAM+idx] = 1.0f;
  }
  if (t < NP) ws[OFF_NU + t] = 0.0f;
  if (t == 0) ws[OFF_MU] = 1.0f;
  if (t < NSUP) {
    float rpv = 0.0f;
    for (int aa = 0; aa < NW; ++aa) {
      const float y = (labSup[t/NSH] == aa) ? 1.0f : 0.0f;
      rpv += 0.1f*y - 1.0f;
    }
    ws[OFF_RP + t] = rpv;
  }
}

// ---------------- A: paired per-way r1_a, X_a = H_a^{-1}, G_a = X_a r1_a --------------
__global__ __launch_bounds__(TPB, 3) void kqpA(const int* __restrict__ labSup, float* __restrict__ ws) {
  const int t = threadIdx.x;
  const int half = (t >= HALF) ? 1 : 0;
  const int th = t - half*HALF;
  const int a = blockIdx.x*2 + half;
  const int tr = th / NTT, tc = th % NTT;
  const bool act = (th < NACT);
  __shared__ __align__(16) float rowbuf[2][NTT][PSTR], colbuf[2][NTT][PSTR], wbuf[2][NTT][PSTR];
  __shared__ __align__(16) float pivinv[2][64];
  __shared__ float zloc[2][NP], dloc[2][NP], r1loc[2][NP];
  __shared__ float pacc[2][NP][NTT];
  const float mu = ws[OFF_MU];
  for (int i = th; i < NP; i += HALF) {
    if (i < NSUP) {
      zloc[half][i] = ws[OFF_Z + i*NW + a];
      dloc[half][i] = ws[OFF_LAM + i*NW + a] / ws[OFF_S + i*NW + a];
    } else { zloc[half][i] = 0.0f; dloc[half][i] = 0.0f; }
  }
  __syncthreads();
  float H[8][8];
  if (act) {
#pragma unroll
    for (int r = 0; r < 8; ++r) {
      const int row = 8*tr + r;
      if (row < NSUP) {
        const float4* ks = (const float4*)(ws + OFF_K + row*NP + 8*tc);
        const float4 x = ks[0], y = ks[1];
        H[r][0]=x.x; H[r][1]=x.y; H[r][2]=x.z; H[r][3]=x.w;
        H[r][4]=y.x; H[r][5]=y.y; H[r][6]=y.z; H[r][7]=y.w;
        if (tc == NTT-1) { H[r][6] = 0.0f; H[r][7] = 0.0f; }   // K pad cols
      } else {
#pragma unroll
        for (int c = 0; c < 8; ++c) H[r][c] = 0.0f;
      }
#pragma unroll
      for (int c = 0; c < 8; ++c) {
        const int col = 8*tc + c;
        if (col == row) H[r][c] += (row < NSUP) ? (10.0f + dloc[half][row]) : 1.0f;
      }
    }
#pragma unroll
    for (int r = 0; r < 8; ++r) {
      float p = 0.0f;
#pragma unroll
      for (int c = 0; c < 8; ++c) p = fmaf(H[r][c], zloc[half][8*tc + c], p);
      pacc[half][8*tr + r][tc] = p;
    }
  }
  __syncthreads();
  if (th < NSUP) {
    float hz = 0.0f;
    for (int q = 0; q < NTT; ++q) hz += pacc[half][th][q];
    const float qz  = hz - dloc[half][th]*zloc[half][th];     // (K + 10I) z
    const float y   = (labSup[th/NSH] == a) ? 1.0f : 0.0f;
    const float svv = ws[OFF_S + th*NW+a], lvv = ws[OFF_LAM + th*NW+a];
    const float rd  = qz - y + lvv + ws[OFF_NU + th];
    const float rc  = svv*lvv - SIGMA*mu;
    const float r1v = -rd + rc/svv;
    ws[OFF_R1 + th*NW+a] = r1v;
    r1loc[half][th] = r1v;
  }
  if (th >= NSUP && th < NP) r1loc[half][th] = 0.0f;
  bgj_invert(H, th, tr, tc, rowbuf[half], colbuf[half], wbuf[half], pivinv[half]);
  if (act) {
    float* Xa = ws + OFF_X + a*XSZ;
#pragma unroll
    for (int r = 0; r < 8; ++r) {
      float4* dst = (float4*)(Xa + (8*tr+r)*NP + 8*tc);
      dst[0] = make_float4(H[r][0],H[r][1],H[r][2],H[r][3]);
      dst[1] = make_float4(H[r][4],H[r][5],H[r][6],H[r][7]);
    }
#pragma unroll
    for (int r = 0; r < 8; ++r) {
      float p = 0.0f;
#pragma unroll
      for (int c = 0; c < 8; ++c) p = fmaf(H[r][c], r1loc[half][8*tc+c], p);
      pacc[half][8*tr+r][tc] = p;
    }
  }
  __syncthreads();
  if (th < NSUP) {
    float g = 0.0f;
    for (int q = 0; q < NTT; ++q) g += pacc[half][th][q];
    ws[OFF_G + th*NW + a] = g;
  }
}

// ---------------- B: sum S, invert, dnu, dz/dlam (all ways), alpha, update -----------
__global__ __launch_bounds__(TPB, 3) void kqpB(float* __restrict__ ws) {
  const int t = threadIdx.x;
  const int half = (t >= HALF) ? 1 : 0;
  const int th = t - half*HALF;
  const int tr = t / NTT, tc = t % NTT;         // full-block tiling for S phases
  const bool act = (t < NACT);
  const int htr = th / NTT, htc = th % NTT;     // per-half tiling for dz phase
  const bool hact = (th < NACT);
  __shared__ __align__(16) float rowbuf[NTT][PSTR], colbuf[NTT][PSTR], wbuf[NTT][PSTR];
  __shared__ __align__(16) float pivinv[64];
  __shared__ float tloc[NP], dnuloc[NP];
  __shared__ float pacc[2][NP][NTT];
  __shared__ float vloc[2][NP];
  __shared__ float zsh[NVAR];
  __shared__ float red[TPB];
  __shared__ unsigned alphaU;
  const float mu = ws[OFF_MU];
  if (t == 0) alphaU = 0x7F800000u;             // +inf
  if (t < NP) {
    float v = 0.0f;
    if (t < NSUP) {
      v = ws[OFF_RP + t];
#pragma unroll
      for (int a = 0; a < NW; ++a) v += ws[OFF_G + t*NW + a];
    }
    tloc[t] = v;
  }
  float Sg[8][8];
  if (act) {
#pragma unroll
    for (int r = 0; r < 8; ++r)
#pragma unroll
      for (int c = 0; c < 8; ++c) Sg[r][c] = 0.0f;
    for (int a = 0; a < NW; ++a) {
      const float* Xa = ws + OFF_X + a*XSZ;
#pragma unroll
      for (int r = 0; r < 8; ++r) {
        const float4* src = (const float4*)(Xa + (8*tr+r)*NP + 8*tc);
        const float4 x = src[0], y = src[1];
        Sg[r][0]+=x.x; Sg[r][1]+=x.y; Sg[r][2]+=x.z; Sg[r][3]+=x.w;
        Sg[r][4]+=y.x; Sg[r][5]+=y.y; Sg[r][6]+=y.z; Sg[r][7]+=y.w;
      }
    }
  }
  bgj_invert(Sg, t, tr, tc, rowbuf, colbuf, wbuf, pivinv);
  if (act) {
#pragma unroll
    for (int r = 0; r < 8; ++r) {
      float p = 0.0f;
#pragma unroll
      for (int c = 0; c < 8; ++c) p = fmaf(Sg[r][c], tloc[8*tc+c], p);
      pacc[0][8*tr+r][tc] = p;
    }
  }
  __syncthreads();
  if (t < NP) {
    float v = 0.0f;
    if (t < NSUP) for (int q = 0; q < NTT; ++q) v += pacc[0][t][q];
    dnuloc[t] = v;
  }
  __syncthreads();
  // dz/dlam for 10 ways: 5 rounds x 2 halves
  for (int rr = 0; rr < 5; ++rr) {
    const int a = half*5 + rr;
    for (int i = th; i < NP; i += HALF)
      vloc[half][i] = (i < NSUP) ? (ws[OFF_R1 + i*NW + a] - dnuloc[i]) : 0.0f;
    __syncthreads();
    if (hact) {
      const float* Xa = ws + OFF_X + a*XSZ;
      const int cb = 8*htc;
#pragma unroll
      for (int r = 0; r < 8; ++r) {
        const float4* src = (const float4*)(Xa + (8*htr+r)*NP + cb);
        const float4 v0 = src[0], v1 = src[1];
        pacc[half][8*htr+r][htc] =
            v0.x*vloc[half][cb+0] + v0.y*vloc[half][cb+1] + v0.z*vloc[half][cb+2] + v0.w*vloc[half][cb+3]
          + v1.x*vloc[half][cb+4] + v1.y*vloc[half][cb+5] + v1.z*vloc[half][cb+6] + v1.w*vloc[half][cb+7];
      }
    }
    __syncthreads();
    if (th < NSUP) {
      float dzv = 0.0f;
      for (int q = 0; q < NTT; ++q) dzv += pacc[half][th][q];
      const float svv = ws[OFF_S + th*NW+a], lvv = ws[OFF_LAM + th*NW+a];
      const float rc  = svv*lvv - SIGMA*mu;
      const float dlv = (lvv*dzv - rc)/svv;
      ws[OFF_DZ + th*NW+a]   = dzv;
      ws[OFF_DLAM + th*NW+a] = dlv;
      const float dsv = -dzv;
      if (dsv < 0.0f) atomicMin(&alphaU, __float_as_uint(-svv/dsv));
      if (dlv < 0.0f) atomicMin(&alphaU, __float_as_uint(-lvv/dlv));
    }
    __syncthreads();
  }
  // alpha + updates
  const float alpha = fminf(1.0f, 0.99f * __uint_as_float(alphaU));
  float part = 0.0f;
  for (int idx = t; idx < NVAR; idx += TPB) {
    const float dzv = ws[OFF_DZ + idx], dlv = ws[OFF_DLAM + idx];
    const float zn = ws[OFF_Z + idx]   + alpha*dzv;
    const float sn = ws[OFF_S + idx]   - alpha*dzv;
    const float ln = ws[OFF_LAM + idx] + alpha*dlv;
    ws[OFF_Z+idx]=zn; ws[OFF_S+idx]=sn; ws[OFF_LAM+idx]=ln;
    zsh[idx] = zn;
    part += sn*ln;
  }
  if (t < NSUP) ws[OFF_NU + t] += alpha * dnuloc[t];
  red[t] = part;
  __syncthreads();
  for (int off = HALF; off > 0; off >>= 1) {
    if (t < off) red[t] += red[t + off];
    __syncthreads();
  }
  if (t == 0) ws[OFF_MU] = red[0] / (float)NVAR;
  if (t < NSUP) {
    float rpv = 0.0f;
#pragma unroll
    for (int a = 0; a < NW; ++a) rpv += zsh[t*NW+a];
    ws[OFF_RP + t] = rpv;
  }
}

// ---------------- Wt[w][d] = scale * sum_s support[s][d] * z[s*10+w] -----------------
__global__ __launch_bounds__(1024) void k_wt(const float* __restrict__ feat,
                                             const float* __restrict__ scale,
                                             float* __restrict__ ws) {
  const int w = blockIdx.x;
  const int dd = threadIdx.x;
  float acc = 0.0f;
  for (int ss = 0; ss < NSUP; ++ss)
    acc += feat[ss*DIM + dd] * ws[OFF_Z + ss*NW + w];
  ws[OFF_WT + w*DIM + dd] = acc * scale[0];
}

// ---------------- logits + log_softmax + loss partials (wave per query row) ----------
__global__ __launch_bounds__(256) void k_logits(const float* __restrict__ feat,
                                                const int* __restrict__ labq,
                                                float* __restrict__ out,
                                                float* __restrict__ ws) {
  const int t = threadIdx.x;
  const int wv = t >> 6, l = t & 63;
  const int q = blockIdx.x*4 + wv;
  __shared__ float wtl[NW][DIM];
  __shared__ float lpart[4];
  for (int idx = t; idx < NW*DIM; idx += 256) wtl[idx >> 10][idx & 1023] = ws[OFF_WT + idx];
  __syncthreads();
  const float* qrow = feat + (size_t)(NSUP + q)*DIM;
  float acc[NW];
#pragma unroll
  for (int w = 0; w < NW; ++w) acc[w] = 0.0f;
#pragma unroll
  for (int c = 0; c < 4; ++c) {
    const float4 qv = *(const float4*)(qrow + c*256 + 4*l);
#pragma unroll
    for (int w = 0; w < NW; ++w) {
      const float4 wvv = *(const float4*)(&wtl[w][c*256 + 4*l]);
      acc[w] += qv.x*wvv.x + qv.y*wvv.y + qv.z*wvv.z + qv.w*wvv.w;
    }
  }
#pragma unroll
  for (int w = 0; w < NW; ++w) {
#pragma unroll
    for (int off = 32; off > 0; off >>= 1)
      acc[w] += __shfl_xor(acc[w], off, 64);
  }
  float m = acc[0];
#pragma unroll
  for (int w = 1; w < NW; ++w) m = fmaxf(m, acc[w]);
  float se = 0.0f;
#pragma unroll
  for (int w = 0; w < NW; ++w) se += expf(acc[w]-m);
  const float lse = m + logf(se);
  const int y = labq[q];
  if (l == 0) {
    float lpy = 0.0f;
#pragma unroll
    for (int w = 0; w < NW; ++w) {
      const float lp = acc[w] - lse;
      out[q*NW + w] = lp;
      if (w == y) lpy = lp;
    }
    lpart[wv] = -lpy;
  }
  __syncthreads();
  if (t == 0) ws[OFF_LP + blockIdx.x] = lpart[0]+lpart[1]+lpart[2]+lpart[3];
}

__global__ __launch_bounds__(1024) void k_loss(float* __restrict__ out, const float* __restrict__ ws) {
  const int t = threadIdx.x;
  __shared__ float red[1024];
  red[t] = ws[OFF_LP + t] + ws[OFF_LP + 1024 + t];
  __syncthreads();
  for (int off = 512; off > 0; off >>= 1) {
    if (t < off) red[t] += red[t + off];
    __syncthreads();
  }
  if (t == 0) out[NQ*NW] = red[0] / (float)NQ;
}

extern "C" void kernel_launch(void* const* d_in, const int* in_sizes, int n_in,
                              void* d_out, int out_size, void* d_ws, size_t ws_size,
                              hipStream_t stream) {
  const float* feat  = (const float*)d_in[0];
  const int*   labS  = (const int*)d_in[1];
  const int*   labQ  = (const int*)d_in[2];
  const float* scale = (const float*)d_in[3];
  float* ws  = (float*)d_ws;
  float* out = (float*)d_out;

  k_gram<<<100, 256, 0, stream>>>(feat, ws);
  kinit<<<1, 1024, 0, stream>>>(labS, ws);
  for (int it = 0; it < 15; ++it) {
    kqpA<<<5, TPB, 0, stream>>>(labS, ws);
    kqpB<<<1, TPB, 0, stream>>>(ws);
  }
  k_wt<<<NW, 1024, 0, stream>>>(feat, scale, ws);
  k_logits<<<NQ/4, 256, 0, stream>>>(feat, labQ, out, ws);
  k_loss<<<1, 1024, 0, stream>>>(out, ws);
}

// Round 4
// 2817.568 us; speedup vs baseline: 1.1307x; 1.1307x over previous
//
#include <hip/hip_runtime.h>

// MetaOptNet head: 15-iteration IPM QP (block-diagonal: 10x 150x150) + logits.
// Round 4: 2-barrier pipelined blocked GJ, per-wave redundant pivot inverse,
// fused Schur/step kernel. TPB=384, launch_bounds(384,2) (proven no-spill).
// Deterministic (only LDS u32 atomicMin used).

#define NW    10
#define NSH   15
#define NSUP  150
#define NQ    8192
#define DIM   1024
#define NVAR  1500
#define NP    152          // padded matrix dim (identity padding)
#define NTT   19           // 8x8 tiles per dim
#define NACT  (NTT*NTT)    // 361 active threads
#define TPB   384
#define SIGMA 0.1f
#define PSTR  68           // LDS panel row stride (64 + 4 pad)

// ws offsets (floats)
#define OFF_K     0        // K stored [150][NP]
#define OFF_Z     22800
#define OFF_S     24300
#define OFF_LAM   25800
#define OFF_NU    27300
#define OFF_R1    27452
#define OFF_DZ    28952
#define OFF_DLAM  30452
#define OFF_RP    32104
#define OFF_MU    32256
#define OFF_LP    32260
#define OFF_WT    34308
#define OFF_G     44548    // G[i*10+a] = (X_a r1_a)_i
#define OFF_SMAT  46048    // S = sum_a X_a (152x152)
#define OFF_X     69152
#define XSZ       (NP*NP)  // 23104

// ---------------- 2-barrier pipelined blocked GJ (19 rank-8 steps) -------------------
// Caller must: build H, then (act && tr==0) -> rowbuf[tc], (act && tc==0) -> colbuf[0][tr],
// then __syncthreads(), then call this. Exits after a barrier.
__device__ __forceinline__ void bgj_core(float (&H)[8][8], const int t, const int tr, const int tc,
                                         float (*rowbuf)[PSTR], float (*colbuf)[NTT][PSTR],
                                         float (*wbuf)[PSTR]) {
  const int lane = t & 63;
  const int pr = lane >> 3, pc = lane & 7;
  const int r8 = t & 7;
  const int wj2 = t >> 3;
  const int jb = wj2 >> 1;
  const int jh4 = (wj2 & 1) << 2;        // 0 or 4
  const bool wact = (t < 8*NTT*2);       // 304 threads for W phase
  const bool act = (t < NACT);
  for (int kb = 0; kb < NTT; ++kb) {
    const int cur = kb & 1, nxt = cur ^ 1;
    // ---- per-wave redundant 8x8 pivot inversion (lane l holds Pinv[l>>3][l&7]) ----
    float p = rowbuf[kb][lane];
#pragma unroll
    for (int pp = 0; pp < 8; ++pp) {
      const float pv   = __shfl(p, pp*9, 64);
      const float d    = 1.0f / pv;
      const float rowv = __shfl(p, pp*8 + pc, 64);
      const float colv = __shfl(p, pr*8 + pp, 64);
      const float nr   = rowv * d;
      float v = fmaf(-colv, nr, p);
      if (pr == pp) v = nr;
      if (pc == pp) v = -colv * d;
      if (pr == pp && pc == pp) v = d;
      p = v;
    }
    float pv8[8];                        // Pinv[r8][q] for this thread's r8
#pragma unroll
    for (int q = 0; q < 8; ++q) pv8[q] = __shfl(p, r8*8 + q, 64);
    // ---- W = Pinv * rowpanel (4 cols per thread), same barrier interval ----
    if (wact) {
      float w0, w1, w2, w3;
      if (jb == kb) {
        w0 = jh4 ? pv8[4] : pv8[0]; w1 = jh4 ? pv8[5] : pv8[1];
        w2 = jh4 ? pv8[6] : pv8[2]; w3 = jh4 ? pv8[7] : pv8[3];
      } else {
        w0 = w1 = w2 = w3 = 0.0f;
#pragma unroll
        for (int q = 0; q < 8; ++q) {
          const float4 x = *(const float4*)(&rowbuf[jb][q*8 + jh4]);
          w0 = fmaf(pv8[q], x.x, w0); w1 = fmaf(pv8[q], x.y, w1);
          w2 = fmaf(pv8[q], x.z, w2); w3 = fmaf(pv8[q], x.w, w3);
        }
      }
      *(float4*)(&wbuf[jb][r8*8 + jh4]) = make_float4(w0, w1, w2, w3);
    }
    __syncthreads();                     // B1: wbuf ready
    // ---- update + store next step's panels ----
    if (act) {
      if (tr == kb) {                    // row panel: H = W
        const float4* wsrc = (const float4*)(&wbuf[tc][0]);
#pragma unroll
        for (int r = 0; r < 8; ++r) {
          const float4 x = wsrc[2*r], y = wsrc[2*r+1];
          H[r][0]=x.x; H[r][1]=x.y; H[r][2]=x.z; H[r][3]=x.w;
          H[r][4]=y.x; H[r][5]=y.y; H[r][6]=y.z; H[r][7]=y.w;
        }
      } else {
        float C[8][8];
        const float4* cs = (const float4*)(&colbuf[cur][tr][0]);
#pragma unroll
        for (int r = 0; r < 8; ++r) {
          const float4 x = cs[2*r], y = cs[2*r+1];
          C[r][0]=x.x; C[r][1]=x.y; C[r][2]=x.z; C[r][3]=x.w;
          C[r][4]=y.x; C[r][5]=y.y; C[r][6]=y.z; C[r][7]=y.w;
        }
        if (tc == kb) {                  // col panel: H = -C*Pinv (zero + update)
#pragma unroll
          for (int r = 0; r < 8; ++r)
#pragma unroll
            for (int c = 0; c < 8; ++c) H[r][c] = 0.0f;
        }
        const float4* wsrc = (const float4*)(&wbuf[tc][0]);
#pragma unroll
        for (int q = 0; q < 8; ++q) {
          const float4 x = wsrc[2*q], y = wsrc[2*q+1];
          const float w0=x.x,w1=x.y,w2=x.z,w3=x.w,w4=y.x,w5=y.y,w6=y.z,w7=y.w;
#pragma unroll
          for (int r = 0; r < 8; ++r) {
            const float cq = C[r][q];
            H[r][0]=fmaf(-cq,w0,H[r][0]); H[r][1]=fmaf(-cq,w1,H[r][1]);
            H[r][2]=fmaf(-cq,w2,H[r][2]); H[r][3]=fmaf(-cq,w3,H[r][3]);
            H[r][4]=fmaf(-cq,w4,H[r][4]); H[r][5]=fmaf(-cq,w5,H[r][5]);
            H[r][6]=fmaf(-cq,w6,H[r][6]); H[r][7]=fmaf(-cq,w7,H[r][7]);
          }
        }
      }
      if (kb < NTT-1) {
        if (tr == kb+1) {
          float4* dst = (float4*)(&rowbuf[tc][0]);
#pragma unroll
          for (int r = 0; r < 8; ++r) {
            dst[2*r]   = make_float4(H[r][0],H[r][1],H[r][2],H[r][3]);
            dst[2*r+1] = make_float4(H[r][4],H[r][5],H[r][6],H[r][7]);
          }
        }
        if (tc == kb+1) {
          float4* dst = (float4*)(&colbuf[nxt][tr][0]);
#pragma unroll
          for (int r = 0; r < 8; ++r) {
            dst[2*r]   = make_float4(H[r][0],H[r][1],H[r][2],H[r][3]);
            dst[2*r+1] = make_float4(H[r][4],H[r][5],H[r][6],H[r][7]);
          }
        }
      }
    }
    __syncthreads();                     // B2: panels for kb+1 ready
  }
}

// ---------------- K = support @ support^T (150x150, stride NP) -----------------------
__global__ __launch_bounds__(256) void k_gram(const float* __restrict__ feat, float* __restrict__ ws) {
  const int bi = blockIdx.x / 10, bj = blockIdx.x % 10;
  const int t = threadIdx.x;
  const int r = t / 15, c = t % 15;
  const bool act = (t < 225);
  __shared__ float As[15][65], Bs[15][65];
  float acc = 0.0f;
  for (int ch = 0; ch < 16; ++ch) {
    for (int idx = t; idx < 960; idx += 256) {
      const int rr = idx >> 6, dd = idx & 63;
      As[rr][dd] = feat[(bi*15+rr)*DIM + ch*64 + dd];
      Bs[rr][dd] = feat[(bj*15+rr)*DIM + ch*64 + dd];
    }
    __syncthreads();
    if (act) {
      for (int dd = 0; dd < 64; ++dd) acc += As[r][dd] * Bs[c][dd];
    }
    __syncthreads();
  }
  if (act) ws[OFF_K + (bi*15+r)*NP + (bj*15+c)] = acc;
}

// ---------------- init ----------------------------------------------------------------
__global__ __launch_bounds__(1024) void kinit(const int* __restrict__ labSup, float* __restrict__ ws) {
  const int t = threadIdx.x;
  for (int idx = t; idx < NVAR; idx += 1024) {
    const int i = idx / NW, aa = idx % NW;
    const float y = (labSup[i/NSH] == aa) ? 1.0f : 0.0f;
    ws[OFF_Z+idx]   = 0.1f*y - 1.0f;
    ws[OFF_S+idx]   = 1.0f;
    ws[OFF_LAM+idx] = 1.0f;
  }
  if (t < NP) ws[OFF_NU + t] = 0.0f;
  if (t == 0) ws[OFF_MU] = 1.0f;
  if (t < NSUP) {
    float rpv = 0.0f;
    for (int aa = 0; aa < NW; ++aa) {
      const float y = (labSup[t/NSH] == aa) ? 1.0f : 0.0f;
      rpv += 0.1f*y - 1.0f;
    }
    ws[OFF_RP + t] = rpv;
  }
}

// ---------------- A: per-way r1_a, X_a = H_a^{-1}, G_a = X_a r1_a ---------------------
__global__ __launch_bounds__(TPB, 2) void kqpA(const int* __restrict__ labSup, float* __restrict__ ws) {
  const int a = blockIdx.x;
  const int t = threadIdx.x;
  const int tr = t / NTT, tc = t % NTT;
  const bool act = (t < NACT);
  __shared__ __align__(16) float rowbuf[NTT][PSTR], colbuf[2][NTT][PSTR], wbuf[NTT][PSTR];
  __shared__ float zloc[NP], dloc[NP], r1loc[NP];
  __shared__ float pacc[NP][NTT];
  const float mu = ws[OFF_MU];
  for (int i = t; i < NP; i += TPB) {
    if (i < NSUP) {
      zloc[i] = ws[OFF_Z + i*NW + a];
      dloc[i] = ws[OFF_LAM + i*NW + a] / ws[OFF_S + i*NW + a];
    } else { zloc[i] = 0.0f; dloc[i] = 0.0f; }
  }
  __syncthreads();
  float H[8][8];
  if (act) {
#pragma unroll
    for (int r = 0; r < 8; ++r) {
      const int row = 8*tr + r;
      if (row < NSUP) {
        const float4* ks = (const float4*)(ws + OFF_K + row*NP + 8*tc);
        const float4 x = ks[0], y = ks[1];
        H[r][0]=x.x; H[r][1]=x.y; H[r][2]=x.z; H[r][3]=x.w;
        H[r][4]=y.x; H[r][5]=y.y; H[r][6]=y.z; H[r][7]=y.w;
        if (tc == NTT-1) { H[r][6] = 0.0f; H[r][7] = 0.0f; }   // K pad cols
      } else {
#pragma unroll
        for (int c = 0; c < 8; ++c) H[r][c] = 0.0f;
      }
#pragma unroll
      for (int c = 0; c < 8; ++c) {
        const int col = 8*tc + c;
        if (col == row) H[r][c] += (row < NSUP) ? (10.0f + dloc[row]) : 1.0f;
      }
    }
#pragma unroll
    for (int r = 0; r < 8; ++r) {
      float p = 0.0f;
#pragma unroll
      for (int c = 0; c < 8; ++c) p = fmaf(H[r][c], zloc[8*tc + c], p);
      pacc[8*tr + r][tc] = p;            // (H z) partials
    }
    // prologue panel stores for bgj step 0
    if (tr == 0) {
      float4* dst = (float4*)(&rowbuf[tc][0]);
#pragma unroll
      for (int r = 0; r < 8; ++r) {
        dst[2*r]   = make_float4(H[r][0],H[r][1],H[r][2],H[r][3]);
        dst[2*r+1] = make_float4(H[r][4],H[r][5],H[r][6],H[r][7]);
      }
    }
    if (tc == 0) {
      float4* dst = (float4*)(&colbuf[0][tr][0]);
#pragma unroll
      for (int r = 0; r < 8; ++r) {
        dst[2*r]   = make_float4(H[r][0],H[r][1],H[r][2],H[r][3]);
        dst[2*r+1] = make_float4(H[r][4],H[r][5],H[r][6],H[r][7]);
      }
    }
  }
  __syncthreads();
  if (t < NSUP) {
    float hz = 0.0f;
    for (int q = 0; q < NTT; ++q) hz += pacc[t][q];
    const float qz  = hz - dloc[t]*zloc[t];                 // (K + 10I) z
    const float y   = (labSup[t/NSH] == a) ? 1.0f : 0.0f;
    const float svv = ws[OFF_S + t*NW+a], lvv = ws[OFF_LAM + t*NW+a];
    const float rd  = qz - y + lvv + ws[OFF_NU + t];
    const float rc  = svv*lvv - SIGMA*mu;
    const float r1v = -rd + rc/svv;
    ws[OFF_R1 + t*NW+a] = r1v;
    r1loc[t] = r1v;
  } else if (t < NP) r1loc[t] = 0.0f;
  bgj_core(H, t, tr, tc, rowbuf, colbuf, wbuf);
  if (act) {
    float* Xa = ws + OFF_X + a*XSZ;
#pragma unroll
    for (int r = 0; r < 8; ++r) {
      float4* dst = (float4*)(Xa + (8*tr+r)*NP + 8*tc);
      dst[0] = make_float4(H[r][0],H[r][1],H[r][2],H[r][3]);
      dst[1] = make_float4(H[r][4],H[r][5],H[r][6],H[r][7]);
    }
#pragma unroll
    for (int r = 0; r < 8; ++r) {
      float p = 0.0f;
#pragma unroll
      for (int c = 0; c < 8; ++c) p = fmaf(H[r][c], r1loc[8*tc+c], p);
      pacc[8*tr+r][tc] = p;              // (X_a r1_a) partials
    }
  }
  __syncthreads();
  if (t < NSUP) {
    float g = 0.0f;
    for (int q = 0; q < NTT; ++q) g += pacc[t][q];
    ws[OFF_G + t*NW + a] = g;
  }
}

// ---------------- k_sum: S = sum_a X_a (parallel across CUs) -------------------------
__global__ __launch_bounds__(256) void k_sum(float* __restrict__ ws) {
  for (int idx = blockIdx.x*256 + threadIdx.x; idx < XSZ; idx += gridDim.x*256) {
    float v = 0.0f;
#pragma unroll
    for (int a = 0; a < NW; ++a) v += ws[OFF_X + a*XSZ + idx];
    ws[OFF_SMAT + idx] = v;
  }
}

// ---------------- B: invert S, dnu, dz/dlam (all ways), alpha, update ----------------
__global__ __launch_bounds__(TPB, 2) void kqpB(float* __restrict__ ws) {
  const int t = threadIdx.x;
  const int tr = t / NTT, tc = t % NTT;
  const bool act = (t < NACT);
  __shared__ __align__(16) float rowbuf[NTT][PSTR], colbuf[2][NTT][PSTR], wbuf[NTT][PSTR];
  __shared__ float tloc[NP], dnuloc[NP], vloc[NP];
  __shared__ float pacc[NP][NTT];
  __shared__ float zsh[NVAR];
  __shared__ float wred[TPB/64];
  __shared__ unsigned alphaU;
  const float mu = ws[OFF_MU];
  if (t == 0) alphaU = 0x7F800000u;      // +inf
  if (t < NP) {
    float v = 0.0f;
    if (t < NSUP) {
      v = ws[OFF_RP + t];
#pragma unroll
      for (int a = 0; a < NW; ++a) v += ws[OFF_G + t*NW + a];
    }
    tloc[t] = v;
  }
  float Sg[8][8];
  if (act) {
#pragma unroll
    for (int r = 0; r < 8; ++r) {
      const float4* ss = (const float4*)(ws + OFF_SMAT + (8*tr+r)*NP + 8*tc);
      const float4 x = ss[0], y = ss[1];
      Sg[r][0]=x.x; Sg[r][1]=x.y; Sg[r][2]=x.z; Sg[r][3]=x.w;
      Sg[r][4]=y.x; Sg[r][5]=y.y; Sg[r][6]=y.z; Sg[r][7]=y.w;
    }
    if (tr == 0) {
      float4* dst = (float4*)(&rowbuf[tc][0]);
#pragma unroll
      for (int r = 0; r < 8; ++r) {
        dst[2*r]   = make_float4(Sg[r][0],Sg[r][1],Sg[r][2],Sg[r][3]);
        dst[2*r+1] = make_float4(Sg[r][4],Sg[r][5],Sg[r][6],Sg[r][7]);
      }
    }
    if (tc == 0) {
      float4* dst = (float4*)(&colbuf[0][tr][0]);
#pragma unroll
      for (int r = 0; r < 8; ++r) {
        dst[2*r]   = make_float4(Sg[r][0],Sg[r][1],Sg[r][2],Sg[r][3]);
        dst[2*r+1] = make_float4(Sg[r][4],Sg[r][5],Sg[r][6],Sg[r][7]);
      }
    }
  }
  __syncthreads();
  bgj_core(Sg, t, tr, tc, rowbuf, colbuf, wbuf);
  if (act) {
#pragma unroll
    for (int r = 0; r < 8; ++r) {
      float p = 0.0f;
#pragma unroll
      for (int c = 0; c < 8; ++c) p = fmaf(Sg[r][c], tloc[8*tc+c], p);
      pacc[8*tr+r][tc] = p;
    }
  }
  __syncthreads();
  if (t < NP) {
    float v = 0.0f;
    if (t < NSUP) for (int q = 0; q < NTT; ++q) v += pacc[t][q];
    dnuloc[t] = v;
  }
  __syncthreads();
  // dz/dlam for the 10 ways, sequential (X_a from L2)
  for (int a = 0; a < NW; ++a) {
    for (int i = t; i < NP; i += TPB)
      vloc[i] = (i < NSUP) ? (ws[OFF_R1 + i*NW + a] - dnuloc[i]) : 0.0f;
    __syncthreads();
    if (act) {
      const float* Xa = ws + OFF_X + a*XSZ;
      const int cb = 8*tc;
#pragma unroll
      for (int r = 0; r < 8; ++r) {
        const float4* src = (const float4*)(Xa + (8*tr+r)*NP + cb);
        const float4 v0 = src[0], v1 = src[1];
        pacc[8*tr+r][tc] =
            v0.x*vloc[cb+0] + v0.y*vloc[cb+1] + v0.z*vloc[cb+2] + v0.w*vloc[cb+3]
          + v1.x*vloc[cb+4] + v1.y*vloc[cb+5] + v1.z*vloc[cb+6] + v1.w*vloc[cb+7];
      }
    }
    __syncthreads();
    if (t < NSUP) {
      float dzv = 0.0f;
      for (int q = 0; q < NTT; ++q) dzv += pacc[t][q];
      const float svv = ws[OFF_S + t*NW+a], lvv = ws[OFF_LAM + t*NW+a];
      const float rc  = svv*lvv - SIGMA*mu;
      const float dlv = (lvv*dzv - rc)/svv;
      ws[OFF_DZ + t*NW+a]   = dzv;
      ws[OFF_DLAM + t*NW+a] = dlv;
      const float dsv = -dzv;
      if (dsv < 0.0f) atomicMin(&alphaU, __float_as_uint(-svv/dsv));
      if (dlv < 0.0f) atomicMin(&alphaU, __float_as_uint(-lvv/dlv));
    }
    __syncthreads();
  }
  // alpha + updates + mu + rp
  const float alpha = fminf(1.0f, 0.99f * __uint_as_float(alphaU));
  float part = 0.0f;
  for (int idx = t; idx < NVAR; idx += TPB) {
    const float dzv = ws[OFF_DZ + idx], dlv = ws[OFF_DLAM + idx];
    const float zn = ws[OFF_Z + idx]   + alpha*dzv;
    const float sn = ws[OFF_S + idx]   - alpha*dzv;
    const float ln = ws[OFF_LAM + idx] + alpha*dlv;
    ws[OFF_Z+idx]=zn; ws[OFF_S+idx]=sn; ws[OFF_LAM+idx]=ln;
    zsh[idx] = zn;
    part += sn*ln;
  }
  if (t < NSUP) ws[OFF_NU + t] += alpha * dnuloc[t];
#pragma unroll
  for (int off = 32; off > 0; off >>= 1) part += __shfl_xor(part, off, 64);
  if ((t & 63) == 0) wred[t >> 6] = part;
  __syncthreads();
  if (t == 0) {
    float s = 0.0f;
#pragma unroll
    for (int wv = 0; wv < TPB/64; ++wv) s += wred[wv];
    ws[OFF_MU] = s / (float)NVAR;
  }
  if (t < NSUP) {
    float rpv = 0.0f;
#pragma unroll
    for (int a = 0; a < NW; ++a) rpv += zsh[t*NW+a];
    ws[OFF_RP + t] = rpv;
  }
}

// ---------------- Wt[w][d] = scale * sum_s support[s][d] * z[s*10+w] -----------------
__global__ __launch_bounds__(1024) void k_wt(const float* __restrict__ feat,
                                             const float* __restrict__ scale,
                                             float* __restrict__ ws) {
  const int w = blockIdx.x;
  const int dd = threadIdx.x;
  float acc = 0.0f;
  for (int ss = 0; ss < NSUP; ++ss)
    acc += feat[ss*DIM + dd] * ws[OFF_Z + ss*NW + w];
  ws[OFF_WT + w*DIM + dd] = acc * scale[0];
}

// ---------------- logits + log_softmax + loss partials (wave per query row) ----------
__global__ __launch_bounds__(256) void k_logits(const float* __restrict__ feat,
                                                const int* __restrict__ labq,
                                                float* __restrict__ out,
                                                float* __restrict__ ws) {
  const int t = threadIdx.x;
  const int wv = t >> 6, l = t & 63;
  const int q = blockIdx.x*4 + wv;
  __shared__ float wtl[NW][DIM];
  __shared__ float lpart[4];
  for (int idx = t; idx < NW*DIM; idx += 256) wtl[idx >> 10][idx & 1023] = ws[OFF_WT + idx];
  __syncthreads();
  const float* qrow = feat + (size_t)(NSUP + q)*DIM;
  float acc[NW];
#pragma unroll
  for (int w = 0; w < NW; ++w) acc[w] = 0.0f;
#pragma unroll
  for (int c = 0; c < 4; ++c) {
    const float4 qv = *(const float4*)(qrow + c*256 + 4*l);
#pragma unroll
    for (int w = 0; w < NW; ++w) {
      const float4 wvv = *(const float4*)(&wtl[w][c*256 + 4*l]);
      acc[w] += qv.x*wvv.x + qv.y*wvv.y + qv.z*wvv.z + qv.w*wvv.w;
    }
  }
#pragma unroll
  for (int w = 0; w < NW; ++w) {
#pragma unroll
    for (int off = 32; off > 0; off >>= 1)
      acc[w] += __shfl_xor(acc[w], off, 64);
  }
  float m = acc[0];
#pragma unroll
  for (int w = 1; w < NW; ++w) m = fmaxf(m, acc[w]);
  float se = 0.0f;
#pragma unroll
  for (int w = 0; w < NW; ++w) se += expf(acc[w]-m);
  const float lse = m + logf(se);
  const int y = labq[q];
  if (l == 0) {
    float lpy = 0.0f;
#pragma unroll
    for (int w = 0; w < NW; ++w) {
      const float lp = acc[w] - lse;
      out[q*NW + w] = lp;
      if (w == y) lpy = lp;
    }
    lpart[wv] = -lpy;
  }
  __syncthreads();
  if (t == 0) ws[OFF_LP + blockIdx.x] = lpart[0]+lpart[1]+lpart[2]+lpart[3];
}

__global__ __launch_bounds__(1024) void k_loss(float* __restrict__ out, const float* __restrict__ ws) {
  const int t = threadIdx.x;
  __shared__ float red[1024];
  red[t] = ws[OFF_LP + t] + ws[OFF_LP + 1024 + t];
  __syncthreads();
  for (int off = 512; off > 0; off >>= 1) {
    if (t < off) red[t] += red[t + off];
    __syncthreads();
  }
  if (t == 0) out[NQ*NW] = red[0] / (float)NQ;
}

extern "C" void kernel_launch(void* const* d_in, const int* in_sizes, int n_in,
                              void* d_out, int out_size, void* d_ws, size_t ws_size,
                              hipStream_t stream) {
  const float* feat  = (const float*)d_in[0];
  const int*   labS  = (const int*)d_in[1];
  const int*   labQ  = (const int*)d_in[2];
  const float* scale = (const float*)d_in[3];
  float* ws  = (float*)d_ws;
  float* out = (float*)d_out;

  k_gram<<<100, 256, 0, stream>>>(feat, ws);
  kinit<<<1, 1024, 0, stream>>>(labS, ws);
  for (int it = 0; it < 15; ++it) {
    kqpA<<<NW, TPB, 0, stream>>>(labS, ws);
    k_sum<<<32, 256, 0, stream>>>(ws);
    kqpB<<<1, TPB, 0, stream>>>(ws);
  }
  k_wt<<<NW, 1024, 0, stream>>>(feat, scale, ws);
  k_logits<<<NQ/4, 256, 0, stream>>>(feat, labQ, out, ws);
  k_loss<<<1, 1024, 0, stream>>>(out, ws);
}

// Round 5
// 2173.636 us; speedup vs baseline: 1.4657x; 1.2962x over previous
//
#include <hip/hip_runtime.h>

// MetaOptNet head: 15-iteration IPM QP (block-diagonal: 10x 150x150) + logits.
// Round 5: 4x8 register tiles / 722 threads (12 waves) for inversions (2x latency
// hiding), 2-barrier pipelined blocked GJ, parallel dz kernel restored.
// Deterministic (only u32 atomicMin used).

#define NW    10
#define NSH   15
#define NSUP  150
#define NQ    8192
#define DIM   1024
#define NVAR  1500
#define NP    152          // padded matrix dim (identity padding)
#define CB    19           // col blocks (8 wide)
#define RB    38           // row blocks (4 tall)
#define NACT2 722          // RB*CB active threads
#define TPB2  768
#define TPB   384
#define NTT   19
#define NACT  (NTT*NTT)
#define SIGMA 0.1f
#define PSTR  68           // rowbuf/wbuf row stride (64 + 4 pad)
#define CTSTR 36           // colbufT stride (32 + 4 pad, 16B-aligned)

// ws offsets (floats)
#define OFF_K     0        // K stored [150][NP]
#define OFF_Z     22800
#define OFF_S     24300
#define OFF_LAM   25800
#define OFF_NU    27300
#define OFF_R1    27452
#define OFF_DZ    28952
#define OFF_DLAM  30452
#define OFF_DNU   31952
#define OFF_RP    32104
#define OFF_MU    32256
#define OFF_ALPHA 32257
#define OFF_LP    32260
#define OFF_WT    34308
#define OFF_G     44548    // G[i*10+a] = (X_a r1_a)_i
#define OFF_SMAT  46048    // S = sum_a X_a (152x152)
#define OFF_X     69152
#define XSZ       (NP*NP)  // 23104

// ------------- 2-barrier pipelined blocked GJ, 4x8 tiles, 19 rank-8 steps ------------
// Caller prologue must store rowbuf (threads trb>>1==0) and colbufT[0] (tcb==0),
// then __syncthreads(). Exits after a barrier with H = inverse tile.
__device__ __forceinline__ void bgj48(float (&H)[4][8], const int t, const int trb, const int tcb,
                                      float (*rowbuf)[PSTR], float (*colbufT)[RB][CTSTR],
                                      float (*wbuf)[PSTR]) {
  const int lane = t & 63;
  const int pr = lane >> 3, pc = lane & 7;
  const int wr  = t & 7;               // W row
  const int wcp = t >> 3;              // col-pair index (need <76)
  const int wcb = wcp >> 2;            // col block
  const int wc2 = (wcp & 3) * 2;       // col within block: 0,2,4,6
  const bool wact = (t < 608);         // 76 pairs x 8 rows
  const bool act  = (t < NACT2);
  for (int kb = 0; kb < CB; ++kb) {
    const int cur = kb & 1, nxt = cur ^ 1;
    // ---- redundant per-wave 8x8 pivot inversion ----
    float p = rowbuf[kb][lane];
#pragma unroll
    for (int pp = 0; pp < 8; ++pp) {
      const float pv   = __shfl(p, pp*9, 64);
      const float d    = 1.0f / pv;
      const float rowv = __shfl(p, pp*8 + pc, 64);
      const float colv = __shfl(p, pr*8 + pp, 64);
      const float nr   = rowv * d;
      float v = fmaf(-colv, nr, p);
      if (pr == pp) v = nr;
      if (pc == pp) v = -colv * d;
      if (pr == pp && pc == pp) v = d;
      p = v;
    }
    float pv8[8];                      // Pinv[wr][q]
#pragma unroll
    for (int q = 0; q < 8; ++q) pv8[q] = __shfl(p, wr*8 + q, 64);
    // ---- W = Pinv * rowpanel (2 cols per thread) ----
    if (wact) {
      float w0, w1;
      if (wcb == kb) { w0 = pv8[wc2]; w1 = pv8[wc2+1]; }
      else {
        w0 = w1 = 0.0f;
#pragma unroll
        for (int q = 0; q < 8; ++q) {
          const float2 rv = *(const float2*)(&rowbuf[wcb][q*8 + wc2]);
          w0 = fmaf(pv8[q], rv.x, w0);
          w1 = fmaf(pv8[q], rv.y, w1);
        }
      }
      *(float2*)(&wbuf[wcb][wr*8 + wc2]) = make_float2(w0, w1);
    }
    __syncthreads();                   // B1: wbuf ready
    if (act) {
      if ((trb >> 1) == kb) {          // row panel: H = W chunk
        const int rbase = (trb & 1) * 4;
#pragma unroll
        for (int r = 0; r < 4; ++r) {
          const float4 x = *(const float4*)(&wbuf[tcb][(rbase+r)*8]);
          const float4 y = *(const float4*)(&wbuf[tcb][(rbase+r)*8+4]);
          H[r][0]=x.x; H[r][1]=x.y; H[r][2]=x.z; H[r][3]=x.w;
          H[r][4]=y.x; H[r][5]=y.y; H[r][6]=y.z; H[r][7]=y.w;
        }
      } else {
        if (tcb == kb) {               // col panel: zero + rank-8 update = -C*Pinv
#pragma unroll
          for (int r = 0; r < 4; ++r)
#pragma unroll
            for (int c = 0; c < 8; ++c) H[r][c] = 0.0f;
        }
#pragma unroll
        for (int q = 0; q < 8; ++q) {
          const float4 cq = *(const float4*)(&colbufT[cur][trb][q*4]);
          const float4 wx = *(const float4*)(&wbuf[tcb][q*8]);
          const float4 wy = *(const float4*)(&wbuf[tcb][q*8+4]);
          const float cr[4] = {cq.x, cq.y, cq.z, cq.w};
          const float wv[8] = {wx.x,wx.y,wx.z,wx.w,wy.x,wy.y,wy.z,wy.w};
#pragma unroll
          for (int r = 0; r < 4; ++r)
#pragma unroll
            for (int c = 0; c < 8; ++c)
              H[r][c] = fmaf(-cr[r], wv[c], H[r][c]);
        }
      }
      if (kb < CB-1) {                 // store next step's panels
        if ((trb >> 1) == kb+1) {
          const int rbase = (trb & 1) * 4;
#pragma unroll
          for (int r = 0; r < 4; ++r) {
            *(float4*)(&rowbuf[tcb][(rbase+r)*8])   = make_float4(H[r][0],H[r][1],H[r][2],H[r][3]);
            *(float4*)(&rowbuf[tcb][(rbase+r)*8+4]) = make_float4(H[r][4],H[r][5],H[r][6],H[r][7]);
          }
        }
        if (tcb == kb+1) {
#pragma unroll
          for (int c = 0; c < 8; ++c)
            *(float4*)(&colbufT[nxt][trb][c*4]) = make_float4(H[0][c],H[1][c],H[2][c],H[3][c]);
        }
      }
    }
    __syncthreads();                   // B2: panels for kb+1 ready
  }
}

// ---------------- K = support @ support^T (150x150, stride NP) -----------------------
__global__ __launch_bounds__(256) void k_gram(const float* __restrict__ feat, float* __restrict__ ws) {
  const int bi = blockIdx.x / 10, bj = blockIdx.x % 10;
  const int t = threadIdx.x;
  const int r = t / 15, c = t % 15;
  const bool act = (t < 225);
  __shared__ float As[15][65], Bs[15][65];
  float acc = 0.0f;
  for (int ch = 0; ch < 16; ++ch) {
    for (int idx = t; idx < 960; idx += 256) {
      const int rr = idx >> 6, dd = idx & 63;
      As[rr][dd] = feat[(bi*15+rr)*DIM + ch*64 + dd];
      Bs[rr][dd] = feat[(bj*15+rr)*DIM + ch*64 + dd];
    }
    __syncthreads();
    if (act) {
      for (int dd = 0; dd < 64; ++dd) acc += As[r][dd] * Bs[c][dd];
    }
    __syncthreads();
  }
  if (act) ws[OFF_K + (bi*15+r)*NP + (bj*15+c)] = acc;
}

// ---------------- init ----------------------------------------------------------------
__global__ __launch_bounds__(1024) void kinit(const int* __restrict__ labSup, float* __restrict__ ws) {
  const int t = threadIdx.x;
  for (int idx = t; idx < NVAR; idx += 1024) {
    const int i = idx / NW, aa = idx % NW;
    const float y = (labSup[i/NSH] == aa) ? 1.0f : 0.0f;
    ws[OFF_Z+idx]   = 0.1f*y - 1.0f;
    ws[OFF_S+idx]   = 1.0f;
    ws[OFF_LAM+idx] = 1.0f;
  }
  if (t < NP) ws[OFF_NU + t] = 0.0f;
  if (t == 0) ws[OFF_MU] = 1.0f;
  if (t < NSUP) {
    float rpv = 0.0f;
    for (int aa = 0; aa < NW; ++aa) {
      const float y = (labSup[t/NSH] == aa) ? 1.0f : 0.0f;
      rpv += 0.1f*y - 1.0f;
    }
    ws[OFF_RP + t] = rpv;
  }
}

// ---------------- A: per-way r1_a, X_a = H_a^{-1}, G_a = X_a r1_a ---------------------
__global__ __launch_bounds__(TPB2, 3) void kqpA(const int* __restrict__ labSup, float* __restrict__ ws) {
  const int a = blockIdx.x;
  const int t = threadIdx.x;
  const int trb = t / CB, tcb = t % CB;
  const bool act = (t < NACT2);
  __shared__ __align__(16) float rowbuf[CB][PSTR], wbuf[CB][PSTR];
  __shared__ __align__(16) float colbufT[2][RB][CTSTR];
  __shared__ float zloc[NP], dloc[NP], r1loc[NP];
  __shared__ float pacc[NP][20];
  const float mu = ws[OFF_MU];
  for (int i = t; i < NP; i += TPB2) {
    if (i < NSUP) {
      zloc[i] = ws[OFF_Z + i*NW + a];
      dloc[i] = ws[OFF_LAM + i*NW + a] / ws[OFF_S + i*NW + a];
    } else { zloc[i] = 0.0f; dloc[i] = 0.0f; }
  }
  __syncthreads();
  float H[4][8];
  if (act) {
#pragma unroll
    for (int r = 0; r < 4; ++r) {
      const int row = 4*trb + r;
      if (row < NSUP) {
        const float4* ks = (const float4*)(ws + OFF_K + row*NP + 8*tcb);
        const float4 x = ks[0], y = ks[1];
        H[r][0]=x.x; H[r][1]=x.y; H[r][2]=x.z; H[r][3]=x.w;
        H[r][4]=y.x; H[r][5]=y.y; H[r][6]=y.z; H[r][7]=y.w;
        if (tcb == CB-1) { H[r][6] = 0.0f; H[r][7] = 0.0f; }   // K pad cols 150,151
      } else {
#pragma unroll
        for (int c = 0; c < 8; ++c) H[r][c] = 0.0f;
      }
#pragma unroll
      for (int c = 0; c < 8; ++c) {
        const int col = 8*tcb + c;
        if (col == row) H[r][c] += (row < NSUP) ? (10.0f + dloc[row]) : 1.0f;
      }
    }
#pragma unroll
    for (int r = 0; r < 4; ++r) {
      float p = 0.0f;
#pragma unroll
      for (int c = 0; c < 8; ++c) p = fmaf(H[r][c], zloc[8*tcb + c], p);
      pacc[4*trb + r][tcb] = p;        // (H z) partials
    }
    // prologue panel stores for step 0
    if ((trb >> 1) == 0) {
      const int rbase = (trb & 1) * 4;
#pragma unroll
      for (int r = 0; r < 4; ++r) {
        *(float4*)(&rowbuf[tcb][(rbase+r)*8])   = make_float4(H[r][0],H[r][1],H[r][2],H[r][3]);
        *(float4*)(&rowbuf[tcb][(rbase+r)*8+4]) = make_float4(H[r][4],H[r][5],H[r][6],H[r][7]);
      }
    }
    if (tcb == 0) {
#pragma unroll
      for (int c = 0; c < 8; ++c)
        *(float4*)(&colbufT[0][trb][c*4]) = make_float4(H[0][c],H[1][c],H[2][c],H[3][c]);
    }
  }
  __syncthreads();
  if (t < NSUP) {
    float hz = 0.0f;
    for (int q = 0; q < CB; ++q) hz += pacc[t][q];
    const float qz  = hz - dloc[t]*zloc[t];                 // (K + 10I) z
    const float y   = (labSup[t/NSH] == a) ? 1.0f : 0.0f;
    const float svv = ws[OFF_S + t*NW+a], lvv = ws[OFF_LAM + t*NW+a];
    const float rd  = qz - y + lvv + ws[OFF_NU + t];
    const float rc  = svv*lvv - SIGMA*mu;
    const float r1v = -rd + rc/svv;
    ws[OFF_R1 + t*NW+a] = r1v;
    r1loc[t] = r1v;
  } else if (t < NP) r1loc[t] = 0.0f;
  bgj48(H, t, trb, tcb, rowbuf, colbufT, wbuf);
  if (act) {
    float* Xa = ws + OFF_X + a*XSZ;
#pragma unroll
    for (int r = 0; r < 4; ++r) {
      float4* dst = (float4*)(Xa + (4*trb+r)*NP + 8*tcb);
      dst[0] = make_float4(H[r][0],H[r][1],H[r][2],H[r][3]);
      dst[1] = make_float4(H[r][4],H[r][5],H[r][6],H[r][7]);
    }
#pragma unroll
    for (int r = 0; r < 4; ++r) {
      float p = 0.0f;
#pragma unroll
      for (int c = 0; c < 8; ++c) p = fmaf(H[r][c], r1loc[8*tcb+c], p);
      pacc[4*trb+r][tcb] = p;          // (X_a r1_a) partials
    }
  }
  __syncthreads();
  if (t < NSUP) {
    float g = 0.0f;
    for (int q = 0; q < CB; ++q) g += pacc[t][q];
    ws[OFF_G + t*NW + a] = g;
  }
}

// ---------------- k_sum: S = sum_a X_a (parallel across CUs) -------------------------
__global__ __launch_bounds__(256) void k_sum(float* __restrict__ ws) {
  for (int idx = blockIdx.x*256 + threadIdx.x; idx < XSZ; idx += gridDim.x*256) {
    float v = 0.0f;
#pragma unroll
    for (int a = 0; a < NW; ++a) v += ws[OFF_X + a*XSZ + idx];
    ws[OFF_SMAT + idx] = v;
  }
}

// ---------------- B: invert S, dnu = S^{-1}(sum G + rp), reset alpha -----------------
__global__ __launch_bounds__(TPB2, 3) void kqpB(float* __restrict__ ws) {
  const int t = threadIdx.x;
  const int trb = t / CB, tcb = t % CB;
  const bool act = (t < NACT2);
  __shared__ __align__(16) float rowbuf[CB][PSTR], wbuf[CB][PSTR];
  __shared__ __align__(16) float colbufT[2][RB][CTSTR];
  __shared__ float tloc[NP];
  __shared__ float pacc[NP][20];
  if (t < NP) {
    float v = 0.0f;
    if (t < NSUP) {
      v = ws[OFF_RP + t];
#pragma unroll
      for (int a = 0; a < NW; ++a) v += ws[OFF_G + t*NW + a];
    }
    tloc[t] = v;
  }
  float Sg[4][8];
  if (act) {
#pragma unroll
    for (int r = 0; r < 4; ++r) {
      const float4* ss = (const float4*)(ws + OFF_SMAT + (4*trb+r)*NP + 8*tcb);
      const float4 x = ss[0], y = ss[1];
      Sg[r][0]=x.x; Sg[r][1]=x.y; Sg[r][2]=x.z; Sg[r][3]=x.w;
      Sg[r][4]=y.x; Sg[r][5]=y.y; Sg[r][6]=y.z; Sg[r][7]=y.w;
    }
    if ((trb >> 1) == 0) {
      const int rbase = (trb & 1) * 4;
#pragma unroll
      for (int r = 0; r < 4; ++r) {
        *(float4*)(&rowbuf[tcb][(rbase+r)*8])   = make_float4(Sg[r][0],Sg[r][1],Sg[r][2],Sg[r][3]);
        *(float4*)(&rowbuf[tcb][(rbase+r)*8+4]) = make_float4(Sg[r][4],Sg[r][5],Sg[r][6],Sg[r][7]);
      }
    }
    if (tcb == 0) {
#pragma unroll
      for (int c = 0; c < 8; ++c)
        *(float4*)(&colbufT[0][trb][c*4]) = make_float4(Sg[0][c],Sg[1][c],Sg[2][c],Sg[3][c]);
    }
  }
  __syncthreads();
  bgj48(Sg, t, trb, tcb, rowbuf, colbufT, wbuf);
  if (act) {
#pragma unroll
    for (int r = 0; r < 4; ++r) {
      float p = 0.0f;
#pragma unroll
      for (int c = 0; c < 8; ++c) p = fmaf(Sg[r][c], tloc[8*tcb+c], p);
      pacc[4*trb+r][tcb] = p;
    }
  }
  __syncthreads();
  if (t < NSUP) {
    float v = 0.0f;
    for (int q = 0; q < CB; ++q) v += pacc[t][q];
    ws[OFF_DNU + t] = v;
  }
  if (t == 0) ((unsigned*)ws)[OFF_ALPHA] = 0x7F800000u;  // +inf
}

// ---------------- K3: dz_a = X_a (r1_a - dnu), dlam, step-length ratios --------------
__global__ __launch_bounds__(TPB) void kqp3(float* __restrict__ ws) {
  const int a = blockIdx.x;
  const int t = threadIdx.x;
  const int tr = t / NTT, tc = t % NTT;
  const bool act = (t < NACT);
  __shared__ float vloc[NP];
  __shared__ float pacc[NP][NTT];
  const float mu = ws[OFF_MU];
  for (int i = t; i < NP; i += TPB)
    vloc[i] = (i < NSUP) ? (ws[OFF_R1 + i*NW + a] - ws[OFF_DNU + i]) : 0.0f;
  __syncthreads();
  if (act) {
    const float* Xa = ws + OFF_X + a*XSZ;
    const int cb = 8*tc;
#pragma unroll
    for (int r = 0; r < 8; ++r) {
      const float4* src = (const float4*)(Xa + (8*tr+r)*NP + cb);
      const float4 v0 = src[0], v1 = src[1];
      pacc[8*tr+r][tc] =
          v0.x*vloc[cb+0] + v0.y*vloc[cb+1] + v0.z*vloc[cb+2] + v0.w*vloc[cb+3]
        + v1.x*vloc[cb+4] + v1.y*vloc[cb+5] + v1.z*vloc[cb+6] + v1.w*vloc[cb+7];
    }
  }
  __syncthreads();
  if (t < NSUP) {
    float dzv = 0.0f;
    for (int q = 0; q < NTT; ++q) dzv += pacc[t][q];
    const float svv = ws[OFF_S + t*NW+a], lvv = ws[OFF_LAM + t*NW+a];
    const float rc  = svv*lvv - SIGMA*mu;
    const float dlv = (lvv*dzv - rc)/svv;
    ws[OFF_DZ + t*NW+a]   = dzv;
    ws[OFF_DLAM + t*NW+a] = dlv;
    unsigned* slot = (unsigned*)(ws) + OFF_ALPHA;
    const float dsv = -dzv;
    if (dsv < 0.0f) atomicMin(slot, __float_as_uint(-svv/dsv));
    if (dlv < 0.0f) atomicMin(slot, __float_as_uint(-lvv/dlv));
  }
}

// ---------------- K4: alpha, update z,s,lam,nu; next mu, rp --------------------------
__global__ __launch_bounds__(1024) void kqp4(float* __restrict__ ws) {
  const int t = threadIdx.x;
  __shared__ float zsh[NVAR];
  __shared__ float red[1024];
  const float am = __uint_as_float(((unsigned*)ws)[OFF_ALPHA]);
  const float alpha = fminf(1.0f, 0.99f * am);
  float part = 0.0f;
  for (int idx = t; idx < NVAR; idx += 1024) {
    const float dzv = ws[OFF_DZ + idx], dlv = ws[OFF_DLAM + idx];
    const float zn = ws[OFF_Z + idx]   + alpha*dzv;
    const float sn = ws[OFF_S + idx]   - alpha*dzv;
    const float ln = ws[OFF_LAM + idx] + alpha*dlv;
    ws[OFF_Z+idx]=zn; ws[OFF_S+idx]=sn; ws[OFF_LAM+idx]=ln;
    zsh[idx] = zn;
    part += sn*ln;
  }
  if (t < NSUP) ws[OFF_NU + t] += alpha * ws[OFF_DNU + t];
  red[t] = part;
  __syncthreads();
  for (int off = 512; off > 0; off >>= 1) {
    if (t < off) red[t] += red[t + off];
    __syncthreads();
  }
  if (t == 0) ws[OFF_MU] = red[0] / (float)NVAR;
  if (t < NSUP) {
    float rpv = 0.0f;
#pragma unroll
    for (int a = 0; a < NW; ++a) rpv += zsh[t*NW+a];
    ws[OFF_RP + t] = rpv;
  }
}

// ---------------- Wt[w][d] = scale * sum_s support[s][d] * z[s*10+w] -----------------
__global__ __launch_bounds__(1024) void k_wt(const float* __restrict__ feat,
                                             const float* __restrict__ scale,
                                             float* __restrict__ ws) {
  const int w = blockIdx.x;
  const int dd = threadIdx.x;
  float acc = 0.0f;
  for (int ss = 0; ss < NSUP; ++ss)
    acc += feat[ss*DIM + dd] * ws[OFF_Z + ss*NW + w];
  ws[OFF_WT + w*DIM + dd] = acc * scale[0];
}

// ---------------- logits + log_softmax + loss partials (wave per query row) ----------
__global__ __launch_bounds__(256) void k_logits(const float* __restrict__ feat,
                                                const int* __restrict__ labq,
                                                float* __restrict__ out,
                                                float* __restrict__ ws) {
  const int t = threadIdx.x;
  const int wv = t >> 6, l = t & 63;
  const int q = blockIdx.x*4 + wv;
  __shared__ float wtl[NW][DIM];
  __shared__ float lpart[4];
  for (int idx = t; idx < NW*DIM; idx += 256) wtl[idx >> 10][idx & 1023] = ws[OFF_WT + idx];
  __syncthreads();
  const float* qrow = feat + (size_t)(NSUP + q)*DIM;
  float acc[NW];
#pragma unroll
  for (int w = 0; w < NW; ++w) acc[w] = 0.0f;
#pragma unroll
  for (int c = 0; c < 4; ++c) {
    const float4 qv = *(const float4*)(qrow + c*256 + 4*l);
#pragma unroll
    for (int w = 0; w < NW; ++w) {
      const float4 wvv = *(const float4*)(&wtl[w][c*256 + 4*l]);
      acc[w] += qv.x*wvv.x + qv.y*wvv.y + qv.z*wvv.z + qv.w*wvv.w;
    }
  }
#pragma unroll
  for (int w = 0; w < NW; ++w) {
#pragma unroll
    for (int off = 32; off > 0; off >>= 1)
      acc[w] += __shfl_xor(acc[w], off, 64);
  }
  float m = acc[0];
#pragma unroll
  for (int w = 1; w < NW; ++w) m = fmaxf(m, acc[w]);
  float se = 0.0f;
#pragma unroll
  for (int w = 0; w < NW; ++w) se += expf(acc[w]-m);
  const float lse = m + logf(se);
  const int y = labq[q];
  if (l == 0) {
    float lpy = 0.0f;
#pragma unroll
    for (int w = 0; w < NW; ++w) {
      const float lp = acc[w] - lse;
      out[q*NW + w] = lp;
      if (w == y) lpy = lp;
    }
    lpart[wv] = -lpy;
  }
  __syncthreads();
  if (t == 0) ws[OFF_LP + blockIdx.x] = lpart[0]+lpart[1]+lpart[2]+lpart[3];
}

__global__ __launch_bounds__(1024) void k_loss(float* __restrict__ out, const float* __restrict__ ws) {
  const int t = threadIdx.x;
  __shared__ float red[1024];
  red[t] = ws[OFF_LP + t] + ws[OFF_LP + 1024 + t];
  __syncthreads();
  for (int off = 512; off > 0; off >>= 1) {
    if (t < off) red[t] += red[t + off];
    __syncthreads();
  }
  if (t == 0) out[NQ*NW] = red[0] / (float)NQ;
}

extern "C" void kernel_launch(void* const* d_in, const int* in_sizes, int n_in,
                              void* d_out, int out_size, void* d_ws, size_t ws_size,
                              hipStream_t stream) {
  const float* feat  = (const float*)d_in[0];
  const int*   labS  = (const int*)d_in[1];
  const int*   labQ  = (const int*)d_in[2];
  const float* scale = (const float*)d_in[3];
  float* ws  = (float*)d_ws;
  float* out = (float*)d_out;

  k_gram<<<100, 256, 0, stream>>>(feat, ws);
  kinit<<<1, 1024, 0, stream>>>(labS, ws);
  for (int it = 0; it < 15; ++it) {
    kqpA<<<NW, TPB2, 0, stream>>>(labS, ws);
    k_sum<<<32, 256, 0, stream>>>(ws);
    kqpB<<<1, TPB2, 0, stream>>>(ws);
    kqp3<<<NW, TPB, 0, stream>>>(ws);
    kqp4<<<1, 1024, 0, stream>>>(ws);
  }
  k_wt<<<NW, 1024, 0, stream>>>(feat, scale, ws);
  k_logits<<<NQ/4, 256, 0, stream>>>(feat, labQ, out, ws);
  k_loss<<<1, 1024, 0, stream>>>(out, ws);
}